// Round 11
// baseline (35622.772 us; speedup 1.0000x reference)
//
#include <hip/hip_runtime.h>

#define TSTEPS 8192
#define NDIM   2048
#define NBLK   128
#define NTHR   256    // 4 waves/block, 4 rows/wave — NO barriers, NO LDS
#define RPB    16     // rows per block
#define NREP   16     // state replicas (round 9: -8%)

typedef float    f32x4 __attribute__((ext_vector_type(4)));
typedef unsigned u32x4 __attribute__((ext_vector_type(4)));

__device__ __forceinline__ unsigned ld_u32_agent(const unsigned* p) {
  return __hip_atomic_load((unsigned*)p, __ATOMIC_RELAXED, __HIP_MEMORY_SCOPE_AGENT);
}
__device__ __forceinline__ void st_u32_agent(unsigned* p, unsigned v) {
  __hip_atomic_store(p, v, __ATOMIC_RELAXED, __HIP_MEMORY_SCOPE_AGENT);
}
__device__ __forceinline__ void st_x4_agent(u32x4* p, u32x4 v) {
  asm volatile("global_store_dwordx4 %0, %1, off sc1" :: "v"(p), "v"(v) : "memory");
}
__device__ __forceinline__ f32x4 ld_w_sync(const f32x4* p) {
  f32x4 r;
  asm volatile("global_load_dwordx4 %0, %1, off\n\ts_waitcnt vmcnt(0)"
               : "=v"(r) : "v"(p));
  return r;
}
// 8 parallel 16B sc1 loads (the lane's whole dot slice), ONE completion wait.
// saddr form: uniform base in SGPR pair, two voffsets cover k=0..3 / 4..7 via
// 13-bit imm offsets (k*1024 bytes).
__device__ __forceinline__ void ld8(unsigned long long sb, unsigned va, unsigned vb,
                                    u32x4& r0, u32x4& r1, u32x4& r2, u32x4& r3,
                                    u32x4& r4, u32x4& r5, u32x4& r6, u32x4& r7) {
  asm volatile(
    "global_load_dwordx4 %0, %[va], %[sb] offset:0    sc1\n\t"
    "global_load_dwordx4 %1, %[va], %[sb] offset:1024 sc1\n\t"
    "global_load_dwordx4 %2, %[va], %[sb] offset:2048 sc1\n\t"
    "global_load_dwordx4 %3, %[va], %[sb] offset:3072 sc1\n\t"
    "global_load_dwordx4 %4, %[vb], %[sb] offset:0    sc1\n\t"
    "global_load_dwordx4 %5, %[vb], %[sb] offset:1024 sc1\n\t"
    "global_load_dwordx4 %6, %[vb], %[sb] offset:2048 sc1\n\t"
    "global_load_dwordx4 %7, %[vb], %[sb] offset:3072 sc1\n\t"
    "s_waitcnt vmcnt(0)"
    : "=&v"(r0), "=&v"(r1), "=&v"(r2), "=&v"(r3),
      "=&v"(r4), "=&v"(r5), "=&v"(r6), "=&v"(r7)
    : [sb]"s"(sb), [va]"v"(va), [vb]"v"(vb)
    : "memory");
}

__global__ void __launch_bounds__(NTHR, 1) esn_persistent(
    const float* __restrict__ u,
    const float* __restrict__ W_in,
    const float* __restrict__ W_res,
    const int* __restrict__ washout_p,
    float* __restrict__ out,
    unsigned* __restrict__ ws)
{
  const int tid  = threadIdx.x;
  const int bid  = blockIdx.x;
  const int wave = tid >> 6;
  const int lane = tid & 63;
  const int rowbase = bid * RPB + wave * 4;   // this wave owns 4 contiguous rows
  const int washout = washout_p[0];

  // ws layout (zeroed each launch): u32[144]=abort; byte 1024+ = NREP replicas
  // x 2 parities x 2048 u32; word[i] = (bf16(x[i])<<16) | step_tag16.
  unsigned* abortw  = ws + 144;
  unsigned* repbase = ws + 256;

  // ---- W preload: 4 rows x 8 chunks (asm-defined; unified-file AGPR moves
  // are cheap — round-10 showed no memory cost for the compiler's placement) ----
  const f32x4* Wr0 = (const f32x4*)(W_res + (size_t)(rowbase + 0) * NDIM) + lane;
  const f32x4* Wr1 = (const f32x4*)(W_res + (size_t)(rowbase + 1) * NDIM) + lane;
  const f32x4* Wr2 = (const f32x4*)(W_res + (size_t)(rowbase + 2) * NDIM) + lane;
  const f32x4* Wr3 = (const f32x4*)(W_res + (size_t)(rowbase + 3) * NDIM) + lane;
  const f32x4 w00 = ld_w_sync(Wr0+0*64), w01 = ld_w_sync(Wr0+1*64), w02 = ld_w_sync(Wr0+2*64), w03 = ld_w_sync(Wr0+3*64);
  const f32x4 w04 = ld_w_sync(Wr0+4*64), w05 = ld_w_sync(Wr0+5*64), w06 = ld_w_sync(Wr0+6*64), w07 = ld_w_sync(Wr0+7*64);
  const f32x4 w10 = ld_w_sync(Wr1+0*64), w11 = ld_w_sync(Wr1+1*64), w12 = ld_w_sync(Wr1+2*64), w13 = ld_w_sync(Wr1+3*64);
  const f32x4 w14 = ld_w_sync(Wr1+4*64), w15 = ld_w_sync(Wr1+5*64), w16 = ld_w_sync(Wr1+6*64), w17 = ld_w_sync(Wr1+7*64);
  const f32x4 w20 = ld_w_sync(Wr2+0*64), w21 = ld_w_sync(Wr2+1*64), w22 = ld_w_sync(Wr2+2*64), w23 = ld_w_sync(Wr2+3*64);
  const f32x4 w24 = ld_w_sync(Wr2+4*64), w25 = ld_w_sync(Wr2+5*64), w26 = ld_w_sync(Wr2+6*64), w27 = ld_w_sync(Wr2+7*64);
  const f32x4 w30 = ld_w_sync(Wr3+0*64), w31 = ld_w_sync(Wr3+1*64), w32 = ld_w_sync(Wr3+2*64), w33 = ld_w_sync(Wr3+3*64);
  const f32x4 w34 = ld_w_sync(Wr3+4*64), w35 = ld_w_sync(Wr3+5*64), w36 = ld_w_sync(Wr3+6*64), w37 = ld_w_sync(Wr3+7*64);
  const float win0 = W_in[rowbase + 0], win1 = W_in[rowbase + 1];
  const float win2 = W_in[rowbase + 2], win3 = W_in[rowbase + 3];

  const unsigned myrep = (unsigned)(bid & (NREP - 1)) * 2u * NDIM; // u32 offset
  const unsigned va = (unsigned)lane * 16u;
  const unsigned vb = va + 4096u;

  unsigned g = 0;        // cumulative retry budget (typ. ~2-3 rounds/step)
  for (int t = 0; t < TSTEPS; ++t) {
    const float ut = u[t];               // issued before poll; hides under it
    // ---- poll the lane's dot slice directly into registers ----
    const unsigned long long sb =
        (unsigned long long)(size_t)(repbase + myrep + (unsigned)(t & 1) * NDIM);
    const unsigned want = (unsigned)t & 0xFFFFu;
    u32x4 r0, r1, r2, r3, r4, r5, r6, r7;
    bool dead = false;
    for (;;) {
      ld8(sb, va, vb, r0, r1, r2, r3, r4, r5, r6, r7);
#define CHK(R) ((R.x ^ want) | (R.y ^ want) | (R.z ^ want) | (R.w ^ want))
      const unsigned d = CHK(r0) | CHK(r1) | CHK(r2) | CHK(r3)
                       | CHK(r4) | CHK(r5) | CHK(r6) | CHK(r7);
#undef CHK
      if (__all((d & 0xFFFFu) == 0u)) break;
      if ((++g & 255u) == 0u) {
        if (ld_u32_agent(abortw) != 0u) { dead = true; break; }
        if (g > (1u << 20)) { st_u32_agent(abortw, 1u); dead = true; break; }
      }
    }
    if (dead) return;                    // wave-uniform; fail loudly, no hang

    // ---- unpack bf16 (high halves) ----
#define UNP(R) { __uint_as_float(R.x & 0xFFFF0000u), __uint_as_float(R.y & 0xFFFF0000u), \
                 __uint_as_float(R.z & 0xFFFF0000u), __uint_as_float(R.w & 0xFFFF0000u) }
    const f32x4 x0 = UNP(r0), x1 = UNP(r1), x2 = UNP(r2), x3 = UNP(r3);
    const f32x4 x4 = UNP(r4), x5 = UNP(r5), x6 = UNP(r6), x7 = UNP(r7);
#undef UNP

    // ---- 4 dot products, all operands in registers ----
    float a0 = 0.f, a1 = 0.f, a2 = 0.f, a3 = 0.f;
#define DOTC(W, X, A) { A += W.x*X.x; A += W.y*X.y; A += W.z*X.z; A += W.w*X.w; }
    DOTC(w00,x0,a0) DOTC(w01,x1,a0) DOTC(w02,x2,a0) DOTC(w03,x3,a0)
    DOTC(w04,x4,a0) DOTC(w05,x5,a0) DOTC(w06,x6,a0) DOTC(w07,x7,a0)
    DOTC(w10,x0,a1) DOTC(w11,x1,a1) DOTC(w12,x2,a1) DOTC(w13,x3,a1)
    DOTC(w14,x4,a1) DOTC(w15,x5,a1) DOTC(w16,x6,a1) DOTC(w17,x7,a1)
    DOTC(w20,x0,a2) DOTC(w21,x1,a2) DOTC(w22,x2,a2) DOTC(w23,x3,a2)
    DOTC(w24,x4,a2) DOTC(w25,x5,a2) DOTC(w26,x6,a2) DOTC(w27,x7,a2)
    DOTC(w30,x0,a3) DOTC(w31,x1,a3) DOTC(w32,x2,a3) DOTC(w33,x3,a3)
    DOTC(w34,x4,a3) DOTC(w35,x5,a3) DOTC(w36,x6,a3) DOTC(w37,x7,a3)
#undef DOTC
    // ---- 4 interleaved butterflies: every lane ends with all 4 row sums ----
#pragma unroll
    for (int off = 32; off > 0; off >>= 1) {
      a0 += __shfl_xor(a0, off, 64);
      a1 += __shfl_xor(a1, off, 64);
      a2 += __shfl_xor(a2, off, 64);
      a3 += __shfl_xor(a3, off, 64);
    }

    // ---- tanh + pack (redundantly in all lanes; no cross-lane traffic) ----
#define FIN(WI, A) (1.0f - __fdividef(2.0f, __expf(2.0f * ((WI) * ut + (A))) + 1.0f))
    const float t0 = FIN(win0, a0), t1 = FIN(win1, a1);
    const float t2 = FIN(win2, a2), t3 = FIN(win3, a3);
#undef FIN
    const unsigned tag = (unsigned)(t + 1);
#define PCK(V) (((__float_as_uint(V) + 0x7fffu + ((__float_as_uint(V) >> 16) & 1u)) \
                 & 0xFFFF0000u) | tag)
    u32x4 P; P.x = PCK(t0); P.y = PCK(t1); P.z = PCK(t2); P.w = PCK(t3);
#undef PCK

    // ---- publish: lanes 0-15 -> one 16B line into each replica (1 wave op);
    // lane 16 -> f32 output slice. All fire-and-forget. ----
    if (lane < NREP) {
      u32x4* dst = (u32x4*)(repbase + ((unsigned)lane * 2u + (unsigned)((t + 1) & 1)) * NDIM)
                   + (bid * 4 + wave);
      st_x4_agent(dst, P);
    } else if (lane == 16 && t >= washout) {
      float4 ov; ov.x = t0; ov.y = t1; ov.z = t2; ov.w = t3;
      *(float4*)(out + (size_t)(t - washout) * NDIM + rowbase) = ov;
    }
  }
}

extern "C" void kernel_launch(void* const* d_in, const int* in_sizes, int n_in,
                              void* d_out, int out_size, void* d_ws, size_t ws_size,
                              hipStream_t stream) {
  const float* u       = (const float*)d_in[0];
  const float* W_in    = (const float*)d_in[1];
  const float* W_res   = (const float*)d_in[2];
  const int*   washout = (const int*)d_in[3];
  float*       out     = (float*)d_out;

  // Zero abort word + all replica parity buffers (tag 0 == valid x0 = zeros).
  (void)hipMemsetAsync(d_ws, 0, 1024 + NREP * 2 * NDIM * 4, stream);

  esn_persistent<<<dim3(NBLK), dim3(NTHR), 0, stream>>>(
      u, W_in, W_res, washout, out, (unsigned*)d_ws);
}

// Round 12
// 22752.527 us; speedup vs baseline: 1.5657x; 1.5657x over previous
//
#include <hip/hip_runtime.h>

#define TSTEPS 8192
#define NDIM   2048
#define NBLK   128
#define NTHR   256    // 4 waves/block, 4 rows/wave; ONE barrier per step
#define RPB    16     // rows per block
#define NREP   16     // state replicas (round 9: fan-in relief)

typedef float    f32x4 __attribute__((ext_vector_type(4)));
typedef unsigned u32x4 __attribute__((ext_vector_type(4)));

__device__ __forceinline__ unsigned ld_u32_agent(const unsigned* p) {
  return __hip_atomic_load((unsigned*)p, __ATOMIC_RELAXED, __HIP_MEMORY_SCOPE_AGENT);
}
__device__ __forceinline__ void st_u32_agent(unsigned* p, unsigned v) {
  __hip_atomic_store(p, v, __ATOMIC_RELAXED, __HIP_MEMORY_SCOPE_AGENT);
}
__device__ __forceinline__ void st_x4_agent(u32x4* p, u32x4 v) {
  asm volatile("global_store_dwordx4 %0, %1, off sc1" :: "v"(p), "v"(v) : "memory");
}
__device__ __forceinline__ f32x4 ld_w_sync(const f32x4* p) {
  f32x4 r;
  asm volatile("global_load_dwordx4 %0, %1, off\n\ts_waitcnt vmcnt(0)"
               : "=v"(r) : "v"(p));
  return r;
}
// Two 16B sc1 loads (the thread's poll slice: 32B), ONE completion wait.
__device__ __forceinline__ void ld2q(unsigned long long sb, unsigned va,
                                     u32x4& r0, u32x4& r1) {
  asm volatile(
    "global_load_dwordx4 %0, %[va], %[sb] offset:0  sc1\n\t"
    "global_load_dwordx4 %1, %[va], %[sb] offset:16 sc1\n\t"
    "s_waitcnt vmcnt(0)"
    : "=&v"(r0), "=&v"(r1)
    : [sb]"s"(sb), [va]"v"(va)
    : "memory");
}

__global__ void __launch_bounds__(NTHR, 1) esn_persistent(
    const float* __restrict__ u,
    const float* __restrict__ W_in,
    const float* __restrict__ W_res,
    const int* __restrict__ washout_p,
    float* __restrict__ out,
    unsigned* __restrict__ ws)
{
  const int tid  = threadIdx.x;
  const int bid  = blockIdx.x;
  const int wave = tid >> 6;
  const int lane = tid & 63;
  const int rowbase = bid * RPB + wave * 4;   // this wave owns 4 contiguous rows
  const int washout = washout_p[0];

  // ws layout (zeroed each launch): u32[144]=abort; byte 1024+ = NREP replicas
  // x 2 parities x 2048 u32; word[i] = (bf16(x[i])<<16) | step_tag16.
  unsigned* abortw  = ws + 144;
  unsigned* repbase = ws + 256;

  __shared__ __align__(16) float x_lds[NDIM];
  __shared__ int s_abort;
  if (tid == 0) s_abort = 0;

  // ---- W preload: 4 rows x 8 chunks, asm-defined (unified VGPR/AGPR file
  // holds this at no memory cost — rounds 10/11 evidence). ----
  const f32x4* Wr0 = (const f32x4*)(W_res + (size_t)(rowbase + 0) * NDIM) + lane;
  const f32x4* Wr1 = (const f32x4*)(W_res + (size_t)(rowbase + 1) * NDIM) + lane;
  const f32x4* Wr2 = (const f32x4*)(W_res + (size_t)(rowbase + 2) * NDIM) + lane;
  const f32x4* Wr3 = (const f32x4*)(W_res + (size_t)(rowbase + 3) * NDIM) + lane;
  const f32x4 w00 = ld_w_sync(Wr0+0*64), w01 = ld_w_sync(Wr0+1*64), w02 = ld_w_sync(Wr0+2*64), w03 = ld_w_sync(Wr0+3*64);
  const f32x4 w04 = ld_w_sync(Wr0+4*64), w05 = ld_w_sync(Wr0+5*64), w06 = ld_w_sync(Wr0+6*64), w07 = ld_w_sync(Wr0+7*64);
  const f32x4 w10 = ld_w_sync(Wr1+0*64), w11 = ld_w_sync(Wr1+1*64), w12 = ld_w_sync(Wr1+2*64), w13 = ld_w_sync(Wr1+3*64);
  const f32x4 w14 = ld_w_sync(Wr1+4*64), w15 = ld_w_sync(Wr1+5*64), w16 = ld_w_sync(Wr1+6*64), w17 = ld_w_sync(Wr1+7*64);
  const f32x4 w20 = ld_w_sync(Wr2+0*64), w21 = ld_w_sync(Wr2+1*64), w22 = ld_w_sync(Wr2+2*64), w23 = ld_w_sync(Wr2+3*64);
  const f32x4 w24 = ld_w_sync(Wr2+4*64), w25 = ld_w_sync(Wr2+5*64), w26 = ld_w_sync(Wr2+6*64), w27 = ld_w_sync(Wr2+7*64);
  const f32x4 w30 = ld_w_sync(Wr3+0*64), w31 = ld_w_sync(Wr3+1*64), w32 = ld_w_sync(Wr3+2*64), w33 = ld_w_sync(Wr3+3*64);
  const f32x4 w34 = ld_w_sync(Wr3+4*64), w35 = ld_w_sync(Wr3+5*64), w36 = ld_w_sync(Wr3+6*64), w37 = ld_w_sync(Wr3+7*64);
  const float win0 = W_in[rowbase + 0], win1 = W_in[rowbase + 1];
  const float win2 = W_in[rowbase + 2], win3 = W_in[rowbase + 3];

  const unsigned myrep = (unsigned)(bid & (NREP - 1)) * 2u * NDIM; // u32 offset
  const unsigned va = (unsigned)tid * 32u;   // this thread's 32B poll slice

  unsigned g = 0;        // cumulative retry budget
  for (int t = 0; t < TSTEPS; ++t) {
    const float ut = u[t];               // uniform, cached; hides under poll
    // ---- cooperative poll+stage: 256 threads x 32B cover the replica ----
    const unsigned long long sb =
        (unsigned long long)(size_t)(repbase + myrep + (unsigned)(t & 1) * NDIM);
    const unsigned want = (unsigned)t & 0xFFFFu;
    u32x4 r0, r1;
    for (;;) {
      ld2q(sb, va, r0, r1);
#define CHK(R) ((R.x ^ want) | (R.y ^ want) | (R.z ^ want) | (R.w ^ want))
      if (((CHK(r0) | CHK(r1)) & 0xFFFFu) == 0u) break;
#undef CHK
      if ((++g & 255u) == 0u) {
        if (ld_u32_agent(abortw) != 0u) { s_abort = 1; break; }
        if (g > (1u << 20)) { st_u32_agent(abortw, 1u); s_abort = 1; break; }
      }
    }
#define UNP(R) { __uint_as_float(R.x & 0xFFFF0000u), __uint_as_float(R.y & 0xFFFF0000u), \
                 __uint_as_float(R.z & 0xFFFF0000u), __uint_as_float(R.w & 0xFFFF0000u) }
    const f32x4 xa = UNP(r0), xb = UNP(r1);
#undef UNP
    ((f32x4*)x_lds)[2 * tid]     = xa;
    ((f32x4*)x_lds)[2 * tid + 1] = xb;
    __syncthreads();                     // S_a — the ONLY barrier per step
    if (s_abort) return;                 // fail loudly instead of hanging

    // ---- 4 dot products per wave: W resident, x from LDS (8 b128 reads) ----
    const f32x4* x4v = (const f32x4*)x_lds + lane;
    const f32x4 x0 = x4v[0*64], x1 = x4v[1*64], x2 = x4v[2*64], x3 = x4v[3*64];
    const f32x4 x4 = x4v[4*64], x5 = x4v[5*64], x6 = x4v[6*64], x7 = x4v[7*64];
    float a0 = 0.f, a1 = 0.f, a2 = 0.f, a3 = 0.f;
#define DOTC(W, X, A) { A += W.x*X.x; A += W.y*X.y; A += W.z*X.z; A += W.w*X.w; }
    DOTC(w00,x0,a0) DOTC(w01,x1,a0) DOTC(w02,x2,a0) DOTC(w03,x3,a0)
    DOTC(w04,x4,a0) DOTC(w05,x5,a0) DOTC(w06,x6,a0) DOTC(w07,x7,a0)
    DOTC(w10,x0,a1) DOTC(w11,x1,a1) DOTC(w12,x2,a1) DOTC(w13,x3,a1)
    DOTC(w14,x4,a1) DOTC(w15,x5,a1) DOTC(w16,x6,a1) DOTC(w17,x7,a1)
    DOTC(w20,x0,a2) DOTC(w21,x1,a2) DOTC(w22,x2,a2) DOTC(w23,x3,a2)
    DOTC(w24,x4,a2) DOTC(w25,x5,a2) DOTC(w26,x6,a2) DOTC(w27,x7,a2)
    DOTC(w30,x0,a3) DOTC(w31,x1,a3) DOTC(w32,x2,a3) DOTC(w33,x3,a3)
    DOTC(w34,x4,a3) DOTC(w35,x5,a3) DOTC(w36,x6,a3) DOTC(w37,x7,a3)
#undef DOTC
    // ---- 4 interleaved butterflies: every lane ends with all 4 row sums ----
#pragma unroll
    for (int off = 32; off > 0; off >>= 1) {
      a0 += __shfl_xor(a0, off, 64);
      a1 += __shfl_xor(a1, off, 64);
      a2 += __shfl_xor(a2, off, 64);
      a3 += __shfl_xor(a3, off, 64);
    }

    // ---- tanh + pack (redundant in all lanes; no cross-lane traffic) ----
#define FIN(WI, A) (1.0f - __fdividef(2.0f, __expf(2.0f * ((WI) * ut + (A))) + 1.0f))
    const float t0 = FIN(win0, a0), t1 = FIN(win1, a1);
    const float t2 = FIN(win2, a2), t3 = FIN(win3, a3);
#undef FIN
    const unsigned tag = (unsigned)(t + 1);
#define PCK(V) (((__float_as_uint(V) + 0x7fffu + ((__float_as_uint(V) >> 16) & 1u)) \
                 & 0xFFFF0000u) | tag)
    u32x4 P; P.x = PCK(t0); P.y = PCK(t1); P.z = PCK(t2); P.w = PCK(t3);
#undef PCK

    // ---- per-wave immediate publish (no second barrier): lanes 0-15 store
    // the wave's 16B quad into each replica; lane 16 writes the f32 out row.
    // Safe without S_b: any x_lds overwrite at t+1 requires some block to have
    // detected ALL of step t, which requires THIS block's every wave to have
    // published t — i.e. finished its dot reads. ----
    if (lane < NREP) {
      u32x4* dst = (u32x4*)(repbase + ((unsigned)lane * 2u + (unsigned)((t + 1) & 1)) * NDIM)
                   + (bid * 4 + wave);
      st_x4_agent(dst, P);
    } else if (lane == 16 && t >= washout) {
      float4 ov; ov.x = t0; ov.y = t1; ov.z = t2; ov.w = t3;
      *(float4*)(out + (size_t)(t - washout) * NDIM + rowbase) = ov;
    }
  }
}

extern "C" void kernel_launch(void* const* d_in, const int* in_sizes, int n_in,
                              void* d_out, int out_size, void* d_ws, size_t ws_size,
                              hipStream_t stream) {
  const float* u       = (const float*)d_in[0];
  const float* W_in    = (const float*)d_in[1];
  const float* W_res   = (const float*)d_in[2];
  const int*   washout = (const int*)d_in[3];
  float*       out     = (float*)d_out;

  // Zero abort word + all replica parity buffers (tag 0 == valid x0 = zeros).
  // Captured in the graph, so every replay starts from identical state.
  (void)hipMemsetAsync(d_ws, 0, 1024 + NREP * 2 * NDIM * 4, stream);

  esn_persistent<<<dim3(NBLK), dim3(NTHR), 0, stream>>>(
      u, W_in, W_res, washout, out, (unsigned*)d_ws);
}

// Round 13
// 20480.045 us; speedup vs baseline: 1.7394x; 1.1110x over previous
//
#include <hip/hip_runtime.h>

#define TSTEPS 8192
#define NDIM   2048
#define NBLK   64     // half the sync participants: fan-in 32->16 readers/line,
                      // straggler max over 64 not 128 blocks
#define NTHR   512
#define RPB    32     // rows per block; 4 rows per wave
#define NREP   16     // state replicas (round 9: fan-in relief)

typedef float    f32x4 __attribute__((ext_vector_type(4)));
typedef unsigned u32x4 __attribute__((ext_vector_type(4)));

// Agent-scope (device-coherent, sc1) ops — coherence point is the shared LLC.
__device__ __forceinline__ unsigned ld_u32_agent(const unsigned* p) {
  return __hip_atomic_load((unsigned*)p, __ATOMIC_RELAXED, __HIP_MEMORY_SCOPE_AGENT);
}
__device__ __forceinline__ void st_u32_agent(unsigned* p, unsigned v) {
  __hip_atomic_store(p, v, __ATOMIC_RELAXED, __HIP_MEMORY_SCOPE_AGENT);
}
// One 16B device-coherent load, completion fused in-asm.
__device__ __forceinline__ u32x4 ld_x4_agent(const u32x4* p) {
  u32x4 r;
  asm volatile("global_load_dwordx4 %0, %1, off sc1\n\ts_waitcnt vmcnt(0)"
               : "=v"(r) : "v"(p) : "memory");
  return r;
}
__device__ __forceinline__ void st_x4_agent(u32x4* p, u32x4 v) {
  asm volatile("global_store_dwordx4 %0, %1, off sc1" :: "v"(p), "v"(v) : "memory");
}
// W preload: value is an ASM OUTPUT (cannot be re-materialized as a reload).
__device__ __forceinline__ f32x4 ld_w_sync(const f32x4* p) {
  f32x4 r;
  asm volatile("global_load_dwordx4 %0, %1, off\n\ts_waitcnt vmcnt(0)"
               : "=v"(r) : "v"(p));
  return r;
}

__global__ void __launch_bounds__(NTHR, 1) esn_persistent(
    const float* __restrict__ u,
    const float* __restrict__ W_in,
    const float* __restrict__ W_res,
    const int* __restrict__ washout_p,
    float* __restrict__ out,
    unsigned* __restrict__ ws)
{
  const int tid  = threadIdx.x;
  const int bid  = blockIdx.x;
  const int wave = tid >> 6;
  const int lane = tid & 63;
  const int rowbase = bid * RPB + wave * 4;  // this wave owns 4 contiguous rows
  const int washout = washout_p[0];

  // ws layout (zeroed each launch): u32[144]=abort; byte 1024+ = NREP replicas
  // x 2 parities x 2048 u32; word[i] = (bf16(x[i])<<16) | step_tag16.
  unsigned* abortw  = ws + 144;
  unsigned* repbase = ws + 256;

  __shared__ __align__(16) float    x_lds[NDIM];
  __shared__ __align__(16) unsigned xpack_lds[RPB];  // 32 packed words (2 lines)
  __shared__ __align__(16) float    xval_lds[RPB];   // 32 f32 values (out row)
  __shared__ int s_abort;
  if (tid == 0) s_abort = 0;

  // ---- W preload: 4 rows x 8 chunks = 128 f32/thread, asm-defined (unified
  // VGPR/AGPR file absorbs this with no memory cost — rounds 10/11). ----
  const f32x4* Wr0 = (const f32x4*)(W_res + (size_t)(rowbase + 0) * NDIM) + lane;
  const f32x4* Wr1 = (const f32x4*)(W_res + (size_t)(rowbase + 1) * NDIM) + lane;
  const f32x4* Wr2 = (const f32x4*)(W_res + (size_t)(rowbase + 2) * NDIM) + lane;
  const f32x4* Wr3 = (const f32x4*)(W_res + (size_t)(rowbase + 3) * NDIM) + lane;
  const f32x4 w00 = ld_w_sync(Wr0+0*64), w01 = ld_w_sync(Wr0+1*64), w02 = ld_w_sync(Wr0+2*64), w03 = ld_w_sync(Wr0+3*64);
  const f32x4 w04 = ld_w_sync(Wr0+4*64), w05 = ld_w_sync(Wr0+5*64), w06 = ld_w_sync(Wr0+6*64), w07 = ld_w_sync(Wr0+7*64);
  const f32x4 w10 = ld_w_sync(Wr1+0*64), w11 = ld_w_sync(Wr1+1*64), w12 = ld_w_sync(Wr1+2*64), w13 = ld_w_sync(Wr1+3*64);
  const f32x4 w14 = ld_w_sync(Wr1+4*64), w15 = ld_w_sync(Wr1+5*64), w16 = ld_w_sync(Wr1+6*64), w17 = ld_w_sync(Wr1+7*64);
  const f32x4 w20 = ld_w_sync(Wr2+0*64), w21 = ld_w_sync(Wr2+1*64), w22 = ld_w_sync(Wr2+2*64), w23 = ld_w_sync(Wr2+3*64);
  const f32x4 w24 = ld_w_sync(Wr2+4*64), w25 = ld_w_sync(Wr2+5*64), w26 = ld_w_sync(Wr2+6*64), w27 = ld_w_sync(Wr2+7*64);
  const f32x4 w30 = ld_w_sync(Wr3+0*64), w31 = ld_w_sync(Wr3+1*64), w32 = ld_w_sync(Wr3+2*64), w33 = ld_w_sync(Wr3+3*64);
  const f32x4 w34 = ld_w_sync(Wr3+4*64), w35 = ld_w_sync(Wr3+5*64), w36 = ld_w_sync(Wr3+6*64), w37 = ld_w_sync(Wr3+7*64);
  const float win0 = W_in[rowbase + 0], win1 = W_in[rowbase + 1];
  const float win2 = W_in[rowbase + 2], win3 = W_in[rowbase + 3];

  // This block polls ONLY its private replica: 4 blocks per replica
  // -> 16 readers per 64B line.
  unsigned* myrep0 = repbase + ((unsigned)(bid & (NREP - 1)) * 2u) * NDIM;

  for (int t = 0; t < TSTEPS; ++t) {
    // ---- fused poll+stage (round-9 pattern): ONE dwordx4 per thread,
    // contiguous 16B/thread, retried until all 4 embedded tags == t. ----
    const u32x4* src = (const u32x4*)(myrep0 + (t & 1) * NDIM) + tid;
    const unsigned want = (unsigned)t;
    u32x4 r;
    bool ok;
    {
      unsigned g = 0;
      do {
        r = ld_x4_agent(src);
        ok = ((((r.x ^ want) | (r.y ^ want)) |
               ((r.z ^ want) | (r.w ^ want))) & 0xFFFFu) == 0u;
        if (!ok && ((++g & 255u) == 0u)) {
          if (ld_u32_agent(abortw) != 0u) break;
          if (g > (1u << 20)) { st_u32_agent(abortw, 1u); break; }
        }
      } while (!ok);
    }
    if (!ok) s_abort = 1;
    {
      f32x4 xv;   // unpack bf16 (high 16 bits) -> f32: one AND per element
      xv.x = __uint_as_float(r.x & 0xFFFF0000u);
      xv.y = __uint_as_float(r.y & 0xFFFF0000u);
      xv.z = __uint_as_float(r.z & 0xFFFF0000u);
      xv.w = __uint_as_float(r.w & 0xFFFF0000u);
      ((f32x4*)x_lds)[tid] = xv;         // contiguous: conflict-free
    }
    const float ut = u[t];               // uniform, cached; hides under S_a
    __syncthreads();                     // S_a
    if (s_abort) return;                 // fail loudly instead of hanging

    // ---- 4 dot products per wave: W resident, x from LDS (8 b128 reads) ----
    const f32x4* x4v = (const f32x4*)x_lds + lane;
    const f32x4 x0 = x4v[0*64], x1 = x4v[1*64], x2 = x4v[2*64], x3 = x4v[3*64];
    const f32x4 x4 = x4v[4*64], x5 = x4v[5*64], x6 = x4v[6*64], x7 = x4v[7*64];
    float a0 = 0.f, a1 = 0.f, a2 = 0.f, a3 = 0.f;
#define DOTC(W, X, A) { A += W.x*X.x; A += W.y*X.y; A += W.z*X.z; A += W.w*X.w; }
    DOTC(w00,x0,a0) DOTC(w01,x1,a0) DOTC(w02,x2,a0) DOTC(w03,x3,a0)
    DOTC(w04,x4,a0) DOTC(w05,x5,a0) DOTC(w06,x6,a0) DOTC(w07,x7,a0)
    DOTC(w10,x0,a1) DOTC(w11,x1,a1) DOTC(w12,x2,a1) DOTC(w13,x3,a1)
    DOTC(w14,x4,a1) DOTC(w15,x5,a1) DOTC(w16,x6,a1) DOTC(w17,x7,a1)
    DOTC(w20,x0,a2) DOTC(w21,x1,a2) DOTC(w22,x2,a2) DOTC(w23,x3,a2)
    DOTC(w24,x4,a2) DOTC(w25,x5,a2) DOTC(w26,x6,a2) DOTC(w27,x7,a2)
    DOTC(w30,x0,a3) DOTC(w31,x1,a3) DOTC(w32,x2,a3) DOTC(w33,x3,a3)
    DOTC(w34,x4,a3) DOTC(w35,x5,a3) DOTC(w36,x6,a3) DOTC(w37,x7,a3)
#undef DOTC
    // ---- 4 interleaved butterflies: every lane ends with all 4 row sums ----
#pragma unroll
    for (int off = 32; off > 0; off >>= 1) {
      a0 += __shfl_xor(a0, off, 64);
      a1 += __shfl_xor(a1, off, 64);
      a2 += __shfl_xor(a2, off, 64);
      a3 += __shfl_xor(a3, off, 64);
    }

    // ---- tanh + pack; stage the wave's 16B into LDS for aggregation ----
#define FIN(WI, A) (1.0f - __fdividef(2.0f, __expf(2.0f * ((WI) * ut + (A))) + 1.0f))
    const float t0 = FIN(win0, a0), t1 = FIN(win1, a1);
    const float t2 = FIN(win2, a2), t3 = FIN(win3, a3);
#undef FIN
    if (lane == 17) {                    // any single lane; 17 avoids pub lanes
      const unsigned tag = (unsigned)(t + 1);
#define PCK(V) (((__float_as_uint(V) + 0x7fffu + ((__float_as_uint(V) >> 16) & 1u)) \
                 & 0xFFFF0000u) | tag)
      u32x4 P; P.x = PCK(t0); P.y = PCK(t1); P.z = PCK(t2); P.w = PCK(t3);
#undef PCK
      ((u32x4*)xpack_lds)[wave] = P;
      f32x4 V; V.x = t0; V.y = t1; V.z = t2; V.w = t3;
      ((f32x4*)xval_lds)[wave] = V;
    }
    __syncthreads();                     // S_b

    // ---- aggregated FULL-LINE publish (round-12 lesson: partial-line 16B
    // wave-stores cost 2x WRITE amplification). Threads 0-127: 16 replicas x
    // 2 contiguous 64B lines. Threads 128-135: f32 output row. ----
    if (tid < 8 * NREP) {
      const int rep = tid >> 3, seg = tid & 7;   // 8 x 16B = 128B contiguous
      u32x4* dst = (u32x4*)(repbase + ((unsigned)(rep * 2 + ((t + 1) & 1)) * NDIM))
                   + bid * 8 + seg;
      st_x4_agent(dst, ((const u32x4*)xpack_lds)[seg]);
    } else if (tid < 8 * NREP + 8 && t >= washout) {
      const int seg = tid - 8 * NREP;
      float4* orow = (float4*)(out + (size_t)(t - washout) * NDIM + bid * RPB) + seg;
      const f32x4 vv = ((const f32x4*)xval_lds)[seg];
      float4 v; v.x = vv.x; v.y = vv.y; v.z = vv.z; v.w = vv.w;
      *orow = v;
    }
  }
}

extern "C" void kernel_launch(void* const* d_in, const int* in_sizes, int n_in,
                              void* d_out, int out_size, void* d_ws, size_t ws_size,
                              hipStream_t stream) {
  const float* u       = (const float*)d_in[0];
  const float* W_in    = (const float*)d_in[1];
  const float* W_res   = (const float*)d_in[2];
  const int*   washout = (const int*)d_in[3];
  float*       out     = (float*)d_out;

  // Zero abort word + all replica parity buffers (tag 0 == valid x0 = zeros).
  // Captured in the graph, so every replay starts from identical state.
  (void)hipMemsetAsync(d_ws, 0, 1024 + NREP * 2 * NDIM * 4, stream);

  esn_persistent<<<dim3(NBLK), dim3(NTHR), 0, stream>>>(
      u, W_in, W_res, washout, out, (unsigned*)d_ws);
}

// Round 14
// 18224.648 us; speedup vs baseline: 1.9546x; 1.1238x over previous
//
#include <hip/hip_runtime.h>

#define TSTEPS 8192
#define NDIM   2048
#define NBLK   128
#define NTHR   512
#define RPB    16     // rows per block = NDIM/NBLK; 2 rows per wave (W=64 f32/thr)
#define NREP   32     // state replicas: readers/line 32 -> 16 (round-9 base had 16)

typedef float    f32x4 __attribute__((ext_vector_type(4)));
typedef unsigned u32x4 __attribute__((ext_vector_type(4)));

// Agent-scope (device-coherent, sc1) ops — coherence point is the shared LLC.
__device__ __forceinline__ unsigned ld_u32_agent(const unsigned* p) {
  return __hip_atomic_load((unsigned*)p, __ATOMIC_RELAXED, __HIP_MEMORY_SCOPE_AGENT);
}
__device__ __forceinline__ void st_u32_agent(unsigned* p, unsigned v) {
  __hip_atomic_store(p, v, __ATOMIC_RELAXED, __HIP_MEMORY_SCOPE_AGENT);
}
// One 16B device-coherent load, completion fused in-asm.
__device__ __forceinline__ u32x4 ld_x4_agent(const u32x4* p) {
  u32x4 r;
  asm volatile("global_load_dwordx4 %0, %1, off sc1\n\ts_waitcnt vmcnt(0)"
               : "=v"(r) : "v"(p) : "memory");
  return r;
}
__device__ __forceinline__ void st_x4_agent(u32x4* p, u32x4 v) {
  asm volatile("global_store_dwordx4 %0, %1, off sc1" :: "v"(p), "v"(v) : "memory");
}
// W preload: value is an ASM OUTPUT (cannot be re-materialized as a reload).
__device__ __forceinline__ f32x4 ld_w_sync(const f32x4* p) {
  f32x4 r;
  asm volatile("global_load_dwordx4 %0, %1, off\n\ts_waitcnt vmcnt(0)"
               : "=v"(r) : "v"(p));
  return r;
}

__global__ void __launch_bounds__(NTHR, 1) esn_persistent(
    const float* __restrict__ u,
    const float* __restrict__ W_in,
    const float* __restrict__ W_res,
    const int* __restrict__ washout_p,
    float* __restrict__ out,
    unsigned* __restrict__ ws)
{
  const int tid  = threadIdx.x;
  const int bid  = blockIdx.x;
  const int wave = tid >> 6;
  const int lane = tid & 63;
  const int row0 = bid * RPB + wave * 2;   // this wave owns rows row0, row0+1
  const int washout = washout_p[0];

  // ws layout (zeroed each launch): u32[144]=abort; byte 1024+ = NREP replicas
  // x 2 parities x 2048 u32; word[i] = (bf16(x[i])<<16) | step_tag16.
  unsigned* abortw  = ws + 144;
  unsigned* repbase = ws + 256;       // byte offset 1024

  __shared__ __align__(16) float    x_lds[NDIM];
  __shared__ __align__(16) unsigned xpack_lds[RPB];  // block's 16 packed words (one 64B line)
  __shared__ __align__(16) float    xval_lds[RPB];   // block's 16 f32 values (out row)
  __shared__ int s_abort;
  if (tid == 0) s_abort = 0;

  // ---- W preload into 16 asm-defined f32x4 (2 rows/wave = 64 f32/thread;
  // unified VGPR/AGPR file absorbs this — rounds 9/10 showed no dur cost). ----
  const f32x4* Wr0 = (const f32x4*)(W_res + (size_t)row0 * NDIM) + lane;
  const f32x4* Wr1 = (const f32x4*)(W_res + (size_t)(row0 + 1) * NDIM) + lane;
  const f32x4 w00 = ld_w_sync(Wr0 + 0 * 64), w01 = ld_w_sync(Wr0 + 1 * 64);
  const f32x4 w02 = ld_w_sync(Wr0 + 2 * 64), w03 = ld_w_sync(Wr0 + 3 * 64);
  const f32x4 w04 = ld_w_sync(Wr0 + 4 * 64), w05 = ld_w_sync(Wr0 + 5 * 64);
  const f32x4 w06 = ld_w_sync(Wr0 + 6 * 64), w07 = ld_w_sync(Wr0 + 7 * 64);
  const f32x4 w10 = ld_w_sync(Wr1 + 0 * 64), w11 = ld_w_sync(Wr1 + 1 * 64);
  const f32x4 w12 = ld_w_sync(Wr1 + 2 * 64), w13 = ld_w_sync(Wr1 + 3 * 64);
  const f32x4 w14 = ld_w_sync(Wr1 + 4 * 64), w15 = ld_w_sync(Wr1 + 5 * 64);
  const f32x4 w16 = ld_w_sync(Wr1 + 6 * 64), w17 = ld_w_sync(Wr1 + 7 * 64);
  const float win0 = W_in[row0];
  const float win1 = W_in[row0 + 1];

  // This block polls ONLY its private replica (bid & 31): 4 blocks per replica
  // -> 16 readers per 64B line.
  unsigned* myrep0 = repbase + ((unsigned)(bid & (NREP - 1)) * 2u) * NDIM;

  for (int t = 0; t < TSTEPS; ++t) {
    // ---- fused poll+stage: ONE dwordx4 per thread, contiguous 16B/thread,
    // retried until all 4 embedded tags == t. ----
    const u32x4* src = (const u32x4*)(myrep0 + (t & 1) * NDIM) + tid;
    const unsigned want = (unsigned)t;
    u32x4 r;
    bool ok;
    {
      unsigned g = 0;
      do {
        r = ld_x4_agent(src);
        ok = ((((r.x ^ want) | (r.y ^ want)) |
               ((r.z ^ want) | (r.w ^ want))) & 0xFFFFu) == 0u;
        if (!ok && ((++g & 255u) == 0u)) {
          if (ld_u32_agent(abortw) != 0u) break;
          if (g > (1u << 20)) { st_u32_agent(abortw, 1u); break; }
        }
      } while (!ok);
    }
    if (!ok) s_abort = 1;
    {
      f32x4 xv;   // unpack bf16 (high 16 bits) -> f32: one AND per element
      xv.x = __uint_as_float(r.x & 0xFFFF0000u);
      xv.y = __uint_as_float(r.y & 0xFFFF0000u);
      xv.z = __uint_as_float(r.z & 0xFFFF0000u);
      xv.w = __uint_as_float(r.w & 0xFFFF0000u);
      ((f32x4*)x_lds)[tid] = xv;         // contiguous: conflict-free
    }
    const float ut = u[t];               // uniform, cached; hides under S_a
    __syncthreads();                     // S_a
    if (s_abort) return;                 // fail loudly instead of hanging

    // ---- 2 dot products per wave: W resident, x from LDS. ----
    float a0 = 0.f, b0 = 0.f, a1 = 0.f, b1 = 0.f;
    const f32x4* x4v = (const f32x4*)x_lds + lane;
#define ESN_DOT(WA, WB, K, A, B) { const f32x4 xv = x4v[(K) * 64];            \
      A += WA.x * xv.x; A += WA.y * xv.y; A += WA.z * xv.z; A += WA.w * xv.w; \
      B += WB.x * xv.x; B += WB.y * xv.y; B += WB.z * xv.z; B += WB.w * xv.w; }
    ESN_DOT(w00, w10, 0, a0, a1) ESN_DOT(w01, w11, 1, b0, b1)
    ESN_DOT(w02, w12, 2, a0, a1) ESN_DOT(w03, w13, 3, b0, b1)
    ESN_DOT(w04, w14, 4, a0, a1) ESN_DOT(w05, w15, 5, b0, b1)
    ESN_DOT(w06, w16, 6, a0, a1) ESN_DOT(w07, w17, 7, b0, b1)
#undef ESN_DOT
    const float s0 = a0 + b0;
    const float s1 = a1 + b1;
    // 7-shfl reduce: fold 64->32 for both rows, route row1 to upper half, butterfly.
    const float c0 = s0 + __shfl_xor(s0, 32, 64);
    const float c1 = s1 + __shfl_xor(s1, 32, 64);
    float c = (lane < 32) ? c0 : c1;
#pragma unroll
    for (int off = 16; off > 0; off >>= 1) c += __shfl_xor(c, off, 64);

    if ((lane & 31) == 0) {              // lane 0 -> row0, lane 32 -> row1
      const float wi  = (lane == 0) ? win0 : win1;
      const float pre = wi * ut + c;
      const float e2  = __expf(2.0f * pre);            // tanh = 1 - 2/(e^2x + 1)
      const float th  = 1.0f - __fdividef(2.0f, e2 + 1.0f);
      const int   i   = wave * 2 + (lane >> 5);
      xval_lds[i] = th;
      const unsigned b  = __float_as_uint(th);
      const unsigned bf = (b + 0x7fffu + ((b >> 16) & 1u)) & 0xFFFF0000u; // RNE bf16
      xpack_lds[i] = bf | (unsigned)(t + 1);           // tag t+1 < 2^16
    }
    __syncthreads();                     // S_b

    // ---- aggregated FULL-LINE publish: threads 0-127 store the block's 64B
    // line into all 32 replicas (4 x dwordx4 each), fire-and-forget. ----
    if (tid < 4 * NREP) {
      const int rep = tid >> 2, seg = tid & 3;
      u32x4* dst = (u32x4*)(repbase + ((unsigned)(rep * 2 + ((t + 1) & 1)) * NDIM))
                   + bid * 4 + seg;
      st_x4_agent(dst, ((const u32x4*)xpack_lds)[seg]);
    } else if (tid >= 128 && tid < 132 && t >= washout) {  // output row
      float4* orow = (float4*)(out + (size_t)(t - washout) * NDIM) + bid * 4 + (tid - 128);
      const f32x4 vv = ((const f32x4*)xval_lds)[tid - 128];
      float4 v; v.x = vv.x; v.y = vv.y; v.z = vv.z; v.w = vv.w;
      *orow = v;
    }
  }
}

extern "C" void kernel_launch(void* const* d_in, const int* in_sizes, int n_in,
                              void* d_out, int out_size, void* d_ws, size_t ws_size,
                              hipStream_t stream) {
  const float* u       = (const float*)d_in[0];
  const float* W_in    = (const float*)d_in[1];
  const float* W_res   = (const float*)d_in[2];
  const int*   washout = (const int*)d_in[3];
  float*       out     = (float*)d_out;

  // Zero abort word + all replica parity buffers (tag 0 == valid x0 = zeros).
  // Captured in the graph, so every replay starts from identical state.
  (void)hipMemsetAsync(d_ws, 0, 1024 + NREP * 2 * NDIM * 4, stream);

  esn_persistent<<<dim3(NBLK), dim3(NTHR), 0, stream>>>(
      u, W_in, W_res, washout, out, (unsigned*)d_ws);
}

// Round 15
// 16746.790 us; speedup vs baseline: 2.1271x; 1.0882x over previous
//
#include <hip/hip_runtime.h>

#define TSTEPS 8192
#define NDIM   2048
#define NBLK   128
#define NTHR   512
#define RPB    16     // rows per block = NDIM/NBLK; 2 rows per wave
#define NREP   16     // measured optimum: r6 (1)=18.2ms, r9 (16)=16.7ms, r14 (32)=18.2ms

typedef float    f32x4 __attribute__((ext_vector_type(4)));
typedef unsigned u32x4 __attribute__((ext_vector_type(4)));

// Agent-scope (device-coherent, sc1) ops — coherence point is the shared LLC.
__device__ __forceinline__ unsigned ld_u32_agent(const unsigned* p) {
  return __hip_atomic_load((unsigned*)p, __ATOMIC_RELAXED, __HIP_MEMORY_SCOPE_AGENT);
}
__device__ __forceinline__ void st_u32_agent(unsigned* p, unsigned v) {
  __hip_atomic_store(p, v, __ATOMIC_RELAXED, __HIP_MEMORY_SCOPE_AGENT);
}
// One 16B device-coherent load, completion fused in-asm.
__device__ __forceinline__ u32x4 ld_x4_agent(const u32x4* p) {
  u32x4 r;
  asm volatile("global_load_dwordx4 %0, %1, off sc1\n\ts_waitcnt vmcnt(0)"
               : "=v"(r) : "v"(p) : "memory");
  return r;
}
__device__ __forceinline__ void st_x4_agent(u32x4* p, u32x4 v) {
  asm volatile("global_store_dwordx4 %0, %1, off sc1" :: "v"(p), "v"(v) : "memory");
}
// W preload: value is an ASM OUTPUT (cannot be re-materialized as a reload).
__device__ __forceinline__ f32x4 ld_w_sync(const f32x4* p) {
  f32x4 r;
  asm volatile("global_load_dwordx4 %0, %1, off\n\ts_waitcnt vmcnt(0)"
               : "=v"(r) : "v"(p));
  return r;
}

__global__ void __launch_bounds__(NTHR, 1) esn_persistent(
    const float* __restrict__ u,
    const float* __restrict__ W_in,
    const float* __restrict__ W_res,
    const int* __restrict__ washout_p,
    float* __restrict__ out,
    unsigned* __restrict__ ws)
{
  const int tid  = threadIdx.x;
  const int bid  = blockIdx.x;
  const int wave = tid >> 6;
  const int lane = tid & 63;
  const int row0 = bid * RPB + wave * 2;   // this wave owns rows row0, row0+1
  const int washout = washout_p[0];

  // ws layout (zeroed each launch): u32[144]=abort; byte 1024+ = NREP replicas
  // x 2 parities x 2048 u32; word[i] = (bf16(x[i])<<16) | step_tag16.
  unsigned* abortw  = ws + 144;
  unsigned* repbase = ws + 256;       // byte offset 1024

  __shared__ __align__(16) float    x_lds[NDIM];
  __shared__ __align__(16) unsigned xpack_lds[RPB];  // block's 16 packed words (one 64B line)
  __shared__ __align__(16) float    xval_lds[RPB];   // block's 16 f32 values (out row)
  __shared__ int s_abort;
  if (tid == 0) s_abort = 0;

  // ---- W preload into 16 asm-defined f32x4 regs (2 rows/wave). ----
  const f32x4* Wr0 = (const f32x4*)(W_res + (size_t)row0 * NDIM) + lane;
  const f32x4* Wr1 = (const f32x4*)(W_res + (size_t)(row0 + 1) * NDIM) + lane;
  const f32x4 w00 = ld_w_sync(Wr0 + 0 * 64), w01 = ld_w_sync(Wr0 + 1 * 64);
  const f32x4 w02 = ld_w_sync(Wr0 + 2 * 64), w03 = ld_w_sync(Wr0 + 3 * 64);
  const f32x4 w04 = ld_w_sync(Wr0 + 4 * 64), w05 = ld_w_sync(Wr0 + 5 * 64);
  const f32x4 w06 = ld_w_sync(Wr0 + 6 * 64), w07 = ld_w_sync(Wr0 + 7 * 64);
  const f32x4 w10 = ld_w_sync(Wr1 + 0 * 64), w11 = ld_w_sync(Wr1 + 1 * 64);
  const f32x4 w12 = ld_w_sync(Wr1 + 2 * 64), w13 = ld_w_sync(Wr1 + 3 * 64);
  const f32x4 w14 = ld_w_sync(Wr1 + 4 * 64), w15 = ld_w_sync(Wr1 + 5 * 64);
  const f32x4 w16 = ld_w_sync(Wr1 + 6 * 64), w17 = ld_w_sync(Wr1 + 7 * 64);
  const float win0 = W_in[row0];
  const float win1 = W_in[row0 + 1];

  // This block polls ONLY its private replica (bid & 15): 8 blocks per replica
  // -> 32 readers per 64B line (measured optimum).
  unsigned* myrep0 = repbase + ((unsigned)(bid & (NREP - 1)) * 2u) * NDIM;

  for (int t = 0; t < TSTEPS; ++t) {
    // ---- fused poll+stage: ONE dwordx4 per thread, contiguous 16B/thread,
    // retried until all 4 embedded tags == t. One LLC round trip = barrier. ----
    const u32x4* src = (const u32x4*)(myrep0 + (t & 1) * NDIM) + tid;
    const unsigned want = (unsigned)t;
    u32x4 r;
    bool ok;
    {
      unsigned g = 0;
      do {
        r = ld_x4_agent(src);
        ok = ((((r.x ^ want) | (r.y ^ want)) |
               ((r.z ^ want) | (r.w ^ want))) & 0xFFFFu) == 0u;
        if (!ok && ((++g & 255u) == 0u)) {
          if (ld_u32_agent(abortw) != 0u) break;
          if (g > (1u << 20)) { st_u32_agent(abortw, 1u); break; }
        }
      } while (!ok);
    }
    if (!ok) s_abort = 1;
    {
      f32x4 xv;   // unpack bf16 (high 16 bits) -> f32: one AND per element
      xv.x = __uint_as_float(r.x & 0xFFFF0000u);
      xv.y = __uint_as_float(r.y & 0xFFFF0000u);
      xv.z = __uint_as_float(r.z & 0xFFFF0000u);
      xv.w = __uint_as_float(r.w & 0xFFFF0000u);
      ((f32x4*)x_lds)[tid] = xv;         // contiguous: conflict-free
    }
    const float ut = u[t];               // uniform, cached; hides under S_a
    __syncthreads();                     // S_a
    if (s_abort) return;                 // fail loudly instead of hanging

    // ---- 2 dot products per wave: W resident, x from LDS. ----
    float a0 = 0.f, b0 = 0.f, a1 = 0.f, b1 = 0.f;
    const f32x4* x4v = (const f32x4*)x_lds + lane;
#define ESN_DOT(WA, WB, K, A, B) { const f32x4 xv = x4v[(K) * 64];            \
      A += WA.x * xv.x; A += WA.y * xv.y; A += WA.z * xv.z; A += WA.w * xv.w; \
      B += WB.x * xv.x; B += WB.y * xv.y; B += WB.z * xv.z; B += WB.w * xv.w; }
    ESN_DOT(w00, w10, 0, a0, a1) ESN_DOT(w01, w11, 1, b0, b1)
    ESN_DOT(w02, w12, 2, a0, a1) ESN_DOT(w03, w13, 3, b0, b1)
    ESN_DOT(w04, w14, 4, a0, a1) ESN_DOT(w05, w15, 5, b0, b1)
    ESN_DOT(w06, w16, 6, a0, a1) ESN_DOT(w07, w17, 7, b0, b1)
#undef ESN_DOT
    const float s0 = a0 + b0;
    const float s1 = a1 + b1;
    // 7-shfl reduce: fold 64->32 for both rows, route row1 to upper half, butterfly.
    const float c0 = s0 + __shfl_xor(s0, 32, 64);
    const float c1 = s1 + __shfl_xor(s1, 32, 64);
    float c = (lane < 32) ? c0 : c1;
#pragma unroll
    for (int off = 16; off > 0; off >>= 1) c += __shfl_xor(c, off, 64);

    if ((lane & 31) == 0) {              // lane 0 -> row0, lane 32 -> row1
      const float wi  = (lane == 0) ? win0 : win1;
      const float pre = wi * ut + c;
      const float e2  = __expf(2.0f * pre);            // tanh = 1 - 2/(e^2x + 1)
      const float th  = 1.0f - __fdividef(2.0f, e2 + 1.0f);
      const int   i   = wave * 2 + (lane >> 5);
      xval_lds[i] = th;
      const unsigned b  = __float_as_uint(th);
      const unsigned bf = (b + 0x7fffu + ((b >> 16) & 1u)) & 0xFFFF0000u; // RNE bf16
      xpack_lds[i] = bf | (unsigned)(t + 1);           // tag t+1 < 2^16
    }
    __syncthreads();                     // S_b

    // ---- aggregated FULL-LINE publish: 64 threads (one wave-instruction)
    // store the block's 64B line into all 16 replicas, fire-and-forget. ----
    if (tid < 4 * NREP) {
      const int rep = tid >> 2, seg = tid & 3;
      u32x4* dst = (u32x4*)(repbase + ((unsigned)(rep * 2 + ((t + 1) & 1)) * NDIM))
                   + bid * 4 + seg;
      st_x4_agent(dst, ((const u32x4*)xpack_lds)[seg]);
    } else if (tid >= 64 && tid < 68 && t >= washout) {  // output row (wave 1)
      float4* orow = (float4*)(out + (size_t)(t - washout) * NDIM) + bid * 4 + (tid - 64);
      const f32x4 vv = ((const f32x4*)xval_lds)[tid - 64];
      float4 v; v.x = vv.x; v.y = vv.y; v.z = vv.z; v.w = vv.w;
      *orow = v;
    }
  }
}

extern "C" void kernel_launch(void* const* d_in, const int* in_sizes, int n_in,
                              void* d_out, int out_size, void* d_ws, size_t ws_size,
                              hipStream_t stream) {
  const float* u       = (const float*)d_in[0];
  const float* W_in    = (const float*)d_in[1];
  const float* W_res   = (const float*)d_in[2];
  const int*   washout = (const int*)d_in[3];
  float*       out     = (float*)d_out;

  // Zero abort word + all replica parity buffers (tag 0 == valid x0 = zeros).
  // Captured in the graph, so every replay starts from identical state.
  (void)hipMemsetAsync(d_ws, 0, 1024 + NREP * 2 * NDIM * 4, stream);

  esn_persistent<<<dim3(NBLK), dim3(NTHR), 0, stream>>>(
      u, W_in, W_res, washout, out, (unsigned*)d_ws);
}